// Round 3
// baseline (219.570 us; speedup 1.0000x reference)
//
#include <hip/hip_runtime.h>

// out[n,c,h,w]:
//   c in [0,64)    : x[n, c+64, (h-1)&63, w]
//   c in [64,128)  : x[n, c-64, (h+1)&63, w]
//   c in [128,192) : x[n, c+64, h, (w-1)&63]
//   c in [192,256) : x[n, c-64, h, (w+1)&63]
//
// N=32, C=256, H=64, W=64. One thread per output float4.
// tid bits: [0:3]=w4, [4:9]=h, [10:17]=c, [18:]=n  -> out flat index = 4*tid.
// Each aligned group of 16 lanes holds one full W-row (16 x 4 floats = 64),
// so the W-wrap element lives in a neighbor lane: __shfl(width=16) instead of
// a second global load. Branch on g = c>>6 is wave-uniform (c constant/wave).

typedef float v4f __attribute__((ext_vector_type(4)));

__global__ __launch_bounds__(256) void swap_kernel(const float* __restrict__ x,
                                                   float* __restrict__ out) {
    const int tid = blockIdx.x * blockDim.x + threadIdx.x;
    const int li  = threadIdx.x & 15;      // lane within 16-lane row group
    const int w0  = (tid & 15) << 2;       // 0,4,...,60
    const int h   = (tid >> 4) & 63;
    const int c   = (tid >> 10) & 255;
    const int n   = tid >> 18;
    const int g   = c >> 6;                // wave-uniform

    const long nbase = (long)n << 20;      // n * 256 * 4096
    v4f r;

    if (g == 0) {
        const float* src = x + nbase + ((long)(c + 64) << 12) + (long)(((h - 1) & 63) << 6) + w0;
        r = *reinterpret_cast<const v4f*>(src);
    } else if (g == 1) {
        const float* src = x + nbase + ((long)(c - 64) << 12) + (long)(((h + 1) & 63) << 6) + w0;
        r = *reinterpret_cast<const v4f*>(src);
    } else if (g == 2) {
        // out[w] = row[(w-1)&63]: prev element = lane (li-1)&15 's element 3
        const float* row = x + nbase + ((long)(c + 64) << 12) + (long)(h << 6);
        v4f f = *reinterpret_cast<const v4f*>(row + w0);
        float p = __shfl(f.w, (li + 15) & 15, 16);
        v4f t; t.x = p; t.y = f.x; t.z = f.y; t.w = f.z;
        r = t;
    } else {
        // out[w] = row[(w+1)&63]: next element = lane (li+1)&15 's element 0
        const float* row = x + nbase + ((long)(c - 64) << 12) + (long)(h << 6);
        v4f f = *reinterpret_cast<const v4f*>(row + w0);
        float nx = __shfl(f.x, (li + 1) & 15, 16);
        v4f t; t.x = f.y; t.y = f.z; t.z = f.w; t.w = nx;
        r = t;
    }

    // Output is write-once, never re-read: keep it out of cache.
    __builtin_nontemporal_store(r, reinterpret_cast<v4f*>(out + ((long)tid << 2)));
}

extern "C" void kernel_launch(void* const* d_in, const int* in_sizes, int n_in,
                              void* d_out, int out_size, void* d_ws, size_t ws_size,
                              hipStream_t stream) {
    const float* x   = (const float*)d_in[0];
    float*       out = (float*)d_out;
    const int total_vec4 = (32 * 256 * 64 * 64) / 4;  // 8,388,608
    const int block = 256;
    const int grid  = total_vec4 / block;             // 32768
    swap_kernel<<<grid, block, 0, stream>>>(x, out);
}